// Round 1
// baseline (127.562 us; speedup 1.0000x reference)
//
#include <hip/hip_runtime.h>

#define LOG2E 1.4426950408889634f

constexpr int Bsz = 4096, Ssz = 128, Isz = 64, MOTOR = 32;
constexpr int BT = 8, R = 4, NT = 256;

__global__ void ltc_prep(const float* __restrict__ w, const float* __restrict__ sigma,
                         const float* __restrict__ mu, const float* __restrict__ erev,
                         const float* __restrict__ smask,
                         const float* __restrict__ sw, const float* __restrict__ ssig,
                         const float* __restrict__ smu, const float* __restrict__ serev,
                         const float* __restrict__ ssmask,
                         float2* __restrict__ AB, float* __restrict__ WE,
                         float2* __restrict__ ABs, float* __restrict__ WEs)
{
  int idx = blockIdx.x * blockDim.x + threadIdx.x;
  if (idx < Ssz * Ssz) {
    float wp = w[idx] * smask[idx];
    WE[idx] = wp * erev[idx];           // sign of erev folded in; |WE| = w*mask
    float sg = sigma[idx];
    AB[idx] = make_float2(-sg * LOG2E, sg * mu[idx] * LOG2E);
  } else if (idx < Ssz * Ssz + Isz * Ssz) {
    int k = idx - Ssz * Ssz;
    float wp = sw[k] * ssmask[k];
    WEs[k] = wp * serev[k];
    float sg = ssig[k];
    ABs[k] = make_float2(-sg * LOG2E, sg * smu[k] * LOG2E);
  }
}

__launch_bounds__(NT)
__global__ void ltc_main(const float* __restrict__ inputs, const float* __restrict__ states,
                         const float* __restrict__ gleak, const float* __restrict__ vleak,
                         const float* __restrict__ cmv,
                         const float* __restrict__ iw, const float* __restrict__ ib,
                         const float* __restrict__ ow, const float* __restrict__ ob,
                         const float2* __restrict__ AB, const float* __restrict__ WE,
                         const float2* __restrict__ ABs, const float* __restrict__ WEs,
                         float* __restrict__ out)
{
  __shared__ float vsh[BT][Ssz];
  __shared__ float xsh[BT][Isz];
  const int t = threadIdx.x;
  const int s = t & (Ssz - 1);
  const int g = t >> 7;
  const int b0 = blockIdx.x * BT;
  const int r0 = g * R;

  // stage x = inputs*input_w + input_b and v = states into LDS
  for (int k = t; k < BT * Isz; k += NT) {
    int r = k >> 6, i = k & (Isz - 1);
    xsh[r][i] = inputs[(b0 + r) * Isz + i] * iw[i] + ib[i];
  }
  for (int k = t; k < BT * Ssz; k += NT) {
    int r = k >> 7, ss = k & (Ssz - 1);
    vsh[r][ss] = states[(b0 + r) * Ssz + ss];
  }
  const float cmt = cmv[s] * 6.0f;   // cm / (1.0 / 6)
  const float gl = gleak[s];
  const float gv = gl * vleak[s];
  __syncthreads();

  // ---- sensory contributions (once) ----
  float sn[R], sd[R];
  #pragma unroll
  for (int r = 0; r < R; ++r) { sn[r] = 0.f; sd[r] = 0.f; }
  {
    float2 abc[4]; float wec[4];
    #pragma unroll
    for (int jj = 0; jj < 4; ++jj) { abc[jj] = ABs[jj * Ssz + s]; wec[jj] = WEs[jj * Ssz + s]; }
    for (int i4 = 0; i4 < Isz; i4 += 4) {
      float xv[R][4];
      #pragma unroll
      for (int r = 0; r < R; ++r) {
        float4 xt = *(const float4*)&xsh[r0 + r][i4];   // broadcast read
        xv[r][0] = xt.x; xv[r][1] = xt.y; xv[r][2] = xt.z; xv[r][3] = xt.w;
      }
      float2 abn[4] = {}; float wen[4] = {};
      if (i4 + 4 < Isz) {
        #pragma unroll
        for (int jj = 0; jj < 4; ++jj) { abn[jj] = ABs[(i4 + 4 + jj) * Ssz + s]; wen[jj] = WEs[(i4 + 4 + jj) * Ssz + s]; }
      }
      #pragma unroll
      for (int jj = 0; jj < 4; ++jj) {
        #pragma unroll
        for (int r = 0; r < R; ++r) {
          float arg = fmaf(abc[jj].x, xv[r][jj], abc[jj].y);
          float u = __builtin_amdgcn_exp2f(arg);
          float sig = __builtin_amdgcn_rcpf(1.0f + u);
          sn[r] = fmaf(wec[jj], sig, sn[r]);
          sd[r] = fmaf(fabsf(wec[jj]), sig, sd[r]);
        }
      }
      #pragma unroll
      for (int jj = 0; jj < 4; ++jj) { abc[jj] = abn[jj]; wec[jj] = wen[jj]; }
    }
  }

  // ---- 6 ODE unfolds ----
  float vnew[R];
  for (int it = 0; it < 6; ++it) {
    float num[R], den[R];
    #pragma unroll
    for (int r = 0; r < R; ++r) { num[r] = sn[r]; den[r] = sd[r]; }
    float2 abc[4]; float wec[4];
    #pragma unroll
    for (int jj = 0; jj < 4; ++jj) { abc[jj] = AB[jj * Ssz + s]; wec[jj] = WE[jj * Ssz + s]; }
    for (int j4 = 0; j4 < Ssz; j4 += 4) {
      float vv[R][4];
      #pragma unroll
      for (int r = 0; r < R; ++r) {
        float4 vt = *(const float4*)&vsh[r0 + r][j4];   // broadcast read
        vv[r][0] = vt.x; vv[r][1] = vt.y; vv[r][2] = vt.z; vv[r][3] = vt.w;
      }
      float2 abn[4] = {}; float wen[4] = {};
      if (j4 + 4 < Ssz) {
        #pragma unroll
        for (int jj = 0; jj < 4; ++jj) { abn[jj] = AB[(j4 + 4 + jj) * Ssz + s]; wen[jj] = WE[(j4 + 4 + jj) * Ssz + s]; }
      }
      #pragma unroll
      for (int jj = 0; jj < 4; ++jj) {
        #pragma unroll
        for (int r = 0; r < R; ++r) {
          float arg = fmaf(abc[jj].x, vv[r][jj], abc[jj].y);
          float u = __builtin_amdgcn_exp2f(arg);
          float sig = __builtin_amdgcn_rcpf(1.0f + u);
          num[r] = fmaf(wec[jj], sig, num[r]);
          den[r] = fmaf(fabsf(wec[jj]), sig, den[r]);
        }
      }
      #pragma unroll
      for (int jj = 0; jj < 4; ++jj) { abc[jj] = abn[jj]; wec[jj] = wen[jj]; }
    }
    #pragma unroll
    for (int r = 0; r < R; ++r) {
      float vo = vsh[r0 + r][s];
      float nn = fmaf(cmt, vo, gv) + num[r];
      float dd = cmt + gl + den[r];
      vnew[r] = nn / (dd + 1e-8f);
    }
    __syncthreads();
    #pragma unroll
    for (int r = 0; r < R; ++r) vsh[r0 + r][s] = vnew[r];
    __syncthreads();
  }

  // ---- outputs: [B*32] motor affine, then [B*128] v_pre ----
  #pragma unroll
  for (int r = 0; r < R; ++r) {
    int b = b0 + r0 + r;
    out[Bsz * MOTOR + b * Ssz + s] = vnew[r];
    if (s < MOTOR) out[b * MOTOR + s] = fmaf(vnew[r], ow[s], ob[s]);
  }
}

extern "C" void kernel_launch(void* const* d_in, const int* in_sizes, int n_in,
                              void* d_out, int out_size, void* d_ws, size_t ws_size,
                              hipStream_t stream) {
  const float* inputs = (const float*)d_in[0];
  const float* states = (const float*)d_in[1];
  const float* gleak  = (const float*)d_in[2];
  const float* vleak  = (const float*)d_in[3];
  const float* cmv    = (const float*)d_in[4];
  const float* w      = (const float*)d_in[5];
  const float* sigma  = (const float*)d_in[6];
  const float* mu     = (const float*)d_in[7];
  const float* erev   = (const float*)d_in[8];
  const float* sw     = (const float*)d_in[9];
  const float* ssig   = (const float*)d_in[10];
  const float* smu    = (const float*)d_in[11];
  const float* serev  = (const float*)d_in[12];
  const float* smask  = (const float*)d_in[13];
  const float* ssmask = (const float*)d_in[14];
  const float* iw     = (const float*)d_in[15];
  const float* ib     = (const float*)d_in[16];
  const float* ow     = (const float*)d_in[17];
  const float* ob     = (const float*)d_in[18];

  char* ws = (char*)d_ws;
  float2* AB  = (float2*)ws;                 // 128*128*8  = 131072 B
  float*  WE  = (float*)(ws + 131072);       // 128*128*4  =  65536 B
  float2* ABs = (float2*)(ws + 196608);      //  64*128*8  =  65536 B
  float*  WEs = (float*)(ws + 262144);       //  64*128*4  =  32768 B
  float* out = (float*)d_out;

  ltc_prep<<<(Ssz * Ssz + Isz * Ssz + 255) / 256, 256, 0, stream>>>(
      w, sigma, mu, erev, smask, sw, ssig, smu, serev, ssmask, AB, WE, ABs, WEs);
  ltc_main<<<Bsz / BT, NT, 0, stream>>>(
      inputs, states, gleak, vleak, cmv, iw, ib, ow, ob, AB, WE, ABs, WEs, out);
}

// Round 2
// 124.788 us; speedup vs baseline: 1.0222x; 1.0222x over previous
//
#include <hip/hip_runtime.h>

#define LOG2E 1.4426950408889634f

constexpr int Bsz = 4096, Ssz = 128, Isz = 64, MOTOR = 32;
constexpr int BT = 8, R = 4, NT = 512;   // 512 thr = 128 s x 2 j-halves x 2 row-groups

// ---- prep: fold constants + repack SoA by j-quad ----
// A4[j4*128+s] = (-sigma*log2e) for j=4*j4..4*j4+3 ; B4 = sigma*mu*log2e ; W4 = w*mask*erev
__global__ void ltc_prep(const float* __restrict__ w, const float* __restrict__ sigma,
                         const float* __restrict__ mu, const float* __restrict__ erev,
                         const float* __restrict__ smask,
                         const float* __restrict__ sw, const float* __restrict__ ssig,
                         const float* __restrict__ smu, const float* __restrict__ serev,
                         const float* __restrict__ ssmask,
                         float4* __restrict__ A4, float4* __restrict__ B4, float4* __restrict__ W4,
                         float4* __restrict__ A4s, float4* __restrict__ B4s, float4* __restrict__ W4s)
{
  int idx = blockIdx.x * blockDim.x + threadIdx.x;
  if (idx < (Ssz / 4) * Ssz) {                    // main: 32 j-quads x 128 s
    int j4 = idx >> 7, s = idx & 127;
    float4 a, b, wv;
    #pragma unroll
    for (int jj = 0; jj < 4; ++jj) {
      int e = (j4 * 4 + jj) * Ssz + s;
      float sg = sigma[e];
      (&a.x)[jj] = -sg * LOG2E;
      (&b.x)[jj] = sg * mu[e] * LOG2E;
      (&wv.x)[jj] = w[e] * smask[e] * erev[e];
    }
    A4[idx] = a; B4[idx] = b; W4[idx] = wv;
  } else if (idx < (Ssz / 4) * Ssz + (Isz / 4) * Ssz) {   // sensory: 16 i-quads x 128 s
    int k = idx - (Ssz / 4) * Ssz;
    int i4 = k >> 7, s = k & 127;
    float4 a, b, wv;
    #pragma unroll
    for (int jj = 0; jj < 4; ++jj) {
      int e = (i4 * 4 + jj) * Ssz + s;
      float sg = ssig[e];
      (&a.x)[jj] = -sg * LOG2E;
      (&b.x)[jj] = sg * smu[e] * LOG2E;
      (&wv.x)[jj] = sw[e] * ssmask[e] * serev[e];
    }
    A4s[k] = a; B4s[k] = b; W4s[k] = wv;
  }
}

__launch_bounds__(NT)
__global__ void ltc_main(const float* __restrict__ inputs, const float* __restrict__ states,
                         const float* __restrict__ gleak, const float* __restrict__ vleak,
                         const float* __restrict__ cmv,
                         const float* __restrict__ iw, const float* __restrict__ ib,
                         const float* __restrict__ ow, const float* __restrict__ ob,
                         const float4* __restrict__ A4, const float4* __restrict__ B4,
                         const float4* __restrict__ W4,
                         const float4* __restrict__ A4s, const float4* __restrict__ B4s,
                         const float4* __restrict__ W4s,
                         float* __restrict__ out)
{
  __shared__ float vsh[BT][Ssz];
  __shared__ float xsh[BT][Isz];
  __shared__ float redn[2][2][R][Ssz];
  __shared__ float redd[2][2][R][Ssz];

  const int t = threadIdx.x;
  const int s = t & 127;
  const int jh = (t >> 7) & 1;       // which half of the j (or i) axis
  const int g = t >> 8;              // row group
  const int r0 = g * R;
  const int b0 = blockIdx.x * BT;

  for (int k = t; k < BT * Isz; k += NT) {
    int r = k >> 6, i = k & 63;
    xsh[r][i] = inputs[(b0 + r) * Isz + i] * iw[i] + ib[i];
  }
  for (int k = t; k < BT * Ssz; k += NT) {
    int r = k >> 7, ss = k & 127;
    vsh[r][ss] = states[(b0 + r) * Ssz + ss];
  }
  const float cmt = cmv[s] * 6.0f;       // cm / (1.0/6)
  const float gl = gleak[s];
  const float gv = gl * vleak[s];
  __syncthreads();

  // ---- sensory partial sums over this thread's i-half ----
  float sn[R] = {0.f, 0.f, 0.f, 0.f}, sd[R] = {0.f, 0.f, 0.f, 0.f};
  {
    const int qb = jh * (Isz / 8);       // 8 quads per half
    for (int q = 0; q < Isz / 8; ++q) {
      int iq = qb + q;
      float4 a4 = A4s[iq * Ssz + s];
      float4 b4 = B4s[iq * Ssz + s];
      float4 w4 = W4s[iq * Ssz + s];
      float xv[R][4];
      #pragma unroll
      for (int r = 0; r < R; ++r) {
        float4 xt = *(const float4*)&xsh[r0 + r][iq * 4];   // broadcast read
        xv[r][0] = xt.x; xv[r][1] = xt.y; xv[r][2] = xt.z; xv[r][3] = xt.w;
      }
      #pragma unroll
      for (int jj = 0; jj < 4; ++jj) {
        float av = (&a4.x)[jj], bv = (&b4.x)[jj], wv = (&w4.x)[jj];
        #pragma unroll
        for (int r = 0; r < R; ++r) {
          float arg = fmaf(av, xv[r][jj], bv);
          float u = __builtin_amdgcn_exp2f(arg);
          float sig = __builtin_amdgcn_rcpf(1.0f + u);
          sn[r] = fmaf(wv, sig, sn[r]);
          sd[r] = fmaf(fabsf(wv), sig, sd[r]);
        }
      }
    }
  }

  // ---- 6 ODE unfolds; each thread does its j-half, then LDS pair-reduce ----
  float vnew[R];
  for (int it = 0; it < 6; ++it) {
    float num[R], den[R], vo[R];
    #pragma unroll
    for (int r = 0; r < R; ++r) { num[r] = sn[r]; den[r] = sd[r]; }
    const int qb = jh * (Ssz / 8);       // 16 quads per half
    for (int q = 0; q < Ssz / 8; ++q) {
      int jq = qb + q;
      float4 a4 = A4[jq * Ssz + s];
      float4 b4 = B4[jq * Ssz + s];
      float4 w4 = W4[jq * Ssz + s];
      float vv[R][4];
      #pragma unroll
      for (int r = 0; r < R; ++r) {
        float4 vt = *(const float4*)&vsh[r0 + r][jq * 4];   // broadcast read
        vv[r][0] = vt.x; vv[r][1] = vt.y; vv[r][2] = vt.z; vv[r][3] = vt.w;
      }
      #pragma unroll
      for (int jj = 0; jj < 4; ++jj) {
        float av = (&a4.x)[jj], bv = (&b4.x)[jj], wv = (&w4.x)[jj];
        #pragma unroll
        for (int r = 0; r < R; ++r) {
          float arg = fmaf(av, vv[r][jj], bv);
          float u = __builtin_amdgcn_exp2f(arg);
          float sig = __builtin_amdgcn_rcpf(1.0f + u);
          num[r] = fmaf(wv, sig, num[r]);
          den[r] = fmaf(fabsf(wv), sig, den[r]);
        }
      }
    }
    #pragma unroll
    for (int r = 0; r < R; ++r) {
      vo[r] = vsh[r0 + r][s];            // read BEFORE anyone overwrites vsh
      redn[jh][g][r][s] = num[r];
      redd[jh][g][r][s] = den[r];
    }
    __syncthreads();
    #pragma unroll
    for (int r = 0; r < R; ++r) {
      float fn = num[r] + redn[1 - jh][g][r][s];
      float fd = den[r] + redd[1 - jh][g][r][s];
      float nn = fmaf(cmt, vo[r], gv) + fn;
      float dd = cmt + gl + fd + 1e-8f;
      vnew[r] = nn * __builtin_amdgcn_rcpf(dd);
    }
    if (jh == 0) {
      #pragma unroll
      for (int r = 0; r < R; ++r) vsh[r0 + r][s] = vnew[r];
    }
    __syncthreads();
  }

  // ---- outputs: [B*32] motor affine, then [B*128] v_pre ----
  if (jh == 0) {
    #pragma unroll
    for (int r = 0; r < R; ++r) {
      int b = b0 + r0 + r;
      out[Bsz * MOTOR + b * Ssz + s] = vnew[r];
      if (s < MOTOR) out[b * MOTOR + s] = fmaf(vnew[r], ow[s], ob[s]);
    }
  }
}

extern "C" void kernel_launch(void* const* d_in, const int* in_sizes, int n_in,
                              void* d_out, int out_size, void* d_ws, size_t ws_size,
                              hipStream_t stream) {
  const float* inputs = (const float*)d_in[0];
  const float* states = (const float*)d_in[1];
  const float* gleak  = (const float*)d_in[2];
  const float* vleak  = (const float*)d_in[3];
  const float* cmv    = (const float*)d_in[4];
  const float* w      = (const float*)d_in[5];
  const float* sigma  = (const float*)d_in[6];
  const float* mu     = (const float*)d_in[7];
  const float* erev   = (const float*)d_in[8];
  const float* sw     = (const float*)d_in[9];
  const float* ssig   = (const float*)d_in[10];
  const float* smu    = (const float*)d_in[11];
  const float* serev  = (const float*)d_in[12];
  const float* smask  = (const float*)d_in[13];
  const float* ssmask = (const float*)d_in[14];
  const float* iw     = (const float*)d_in[15];
  const float* ib     = (const float*)d_in[16];
  const float* ow     = (const float*)d_in[17];
  const float* ob     = (const float*)d_in[18];

  char* ws = (char*)d_ws;
  float4* A4  = (float4*)(ws);                   // 32*128*16 = 65536
  float4* B4  = (float4*)(ws + 65536);           // 65536
  float4* W4  = (float4*)(ws + 131072);          // 65536
  float4* A4s = (float4*)(ws + 196608);          // 16*128*16 = 32768
  float4* B4s = (float4*)(ws + 229376);          // 32768
  float4* W4s = (float4*)(ws + 262144);          // 32768  (total 294912 B)
  float* out = (float*)d_out;

  constexpr int prep_items = (Ssz / 4) * Ssz + (Isz / 4) * Ssz;   // 6144
  ltc_prep<<<(prep_items + 255) / 256, 256, 0, stream>>>(
      w, sigma, mu, erev, smask, sw, ssig, smu, serev, ssmask, A4, B4, W4, A4s, B4s, W4s);
  ltc_main<<<Bsz / BT, NT, 0, stream>>>(
      inputs, states, gleak, vleak, cmv, iw, ib, ow, ob, A4, B4, W4, A4s, B4s, W4s, out);
}

// Round 3
// 115.067 us; speedup vs baseline: 1.1086x; 1.0845x over previous
//
#include <hip/hip_runtime.h>

#define LOG2E 1.4426950408889634f

constexpr int Bsz = 4096, Ssz = 128, Isz = 64, MOTOR = 32;
constexpr int BT = 16, R = 4, NT = 512, NQ = 4;   // 512 thr = 128 s x 4 j-quarters

// ---- prep: fold constants + repack SoA by j-quad ----
// A4[j4*128+s] = (-sigma*log2e) for j=4*j4..4*j4+3 ; B4 = sigma*mu*log2e ; W4 = w*mask*erev
__global__ void ltc_prep(const float* __restrict__ w, const float* __restrict__ sigma,
                         const float* __restrict__ mu, const float* __restrict__ erev,
                         const float* __restrict__ smask,
                         const float* __restrict__ sw, const float* __restrict__ ssig,
                         const float* __restrict__ smu, const float* __restrict__ serev,
                         const float* __restrict__ ssmask,
                         float4* __restrict__ A4, float4* __restrict__ B4, float4* __restrict__ W4,
                         float4* __restrict__ A4s, float4* __restrict__ B4s, float4* __restrict__ W4s)
{
  int idx = blockIdx.x * blockDim.x + threadIdx.x;
  if (idx < (Ssz / 4) * Ssz) {                    // main: 32 j-quads x 128 s
    int j4 = idx >> 7, s = idx & 127;
    float4 a, b, wv;
    #pragma unroll
    for (int jj = 0; jj < 4; ++jj) {
      int e = (j4 * 4 + jj) * Ssz + s;
      float sg = sigma[e];
      (&a.x)[jj] = -sg * LOG2E;
      (&b.x)[jj] = sg * mu[e] * LOG2E;
      (&wv.x)[jj] = w[e] * smask[e] * erev[e];
    }
    A4[idx] = a; B4[idx] = b; W4[idx] = wv;
  } else if (idx < (Ssz / 4) * Ssz + (Isz / 4) * Ssz) {   // sensory: 16 i-quads x 128 s
    int k = idx - (Ssz / 4) * Ssz;
    int i4 = k >> 7, s = k & 127;
    float4 a, b, wv;
    #pragma unroll
    for (int jj = 0; jj < 4; ++jj) {
      int e = (i4 * 4 + jj) * Ssz + s;
      float sg = ssig[e];
      (&a.x)[jj] = -sg * LOG2E;
      (&b.x)[jj] = sg * smu[e] * LOG2E;
      (&wv.x)[jj] = sw[e] * ssmask[e] * serev[e];
    }
    A4s[k] = a; B4s[k] = b; W4s[k] = wv;
  }
}

__launch_bounds__(NT, 2)
__global__ void ltc_main(const float* __restrict__ inputs, const float* __restrict__ states,
                         const float* __restrict__ gleak, const float* __restrict__ vleak,
                         const float* __restrict__ cmv,
                         const float* __restrict__ iw, const float* __restrict__ ib,
                         const float* __restrict__ ow, const float* __restrict__ ob,
                         const float4* __restrict__ A4, const float4* __restrict__ B4,
                         const float4* __restrict__ W4,
                         const float4* __restrict__ A4s, const float4* __restrict__ B4s,
                         const float4* __restrict__ W4s,
                         float* __restrict__ out)
{
  __shared__ float vsh[BT][Ssz];
  __shared__ float xsh[BT][Isz];
  __shared__ float redn[NQ][NQ][Ssz];   // [writer-quarter][row-in-chunk][s]
  __shared__ float redd[NQ][NQ][Ssz];

  const int t = threadIdx.x;
  const int s = t & 127;
  const int qt = t >> 7;               // j-quarter 0..3; also row-in-chunk this thread finalizes
  const int b0 = blockIdx.x * BT;

  // stage x = inputs*iw + ib and v = states into LDS
  for (int k = t; k < BT * Isz; k += NT) {
    int r = k >> 6, i = k & 63;
    xsh[r][i] = inputs[(b0 + r) * Isz + i] * iw[i] + ib[i];
  }
  for (int k = t; k < BT * Ssz; k += NT) {
    int r = k >> 7, ss = k & 127;
    vsh[r][ss] = states[(b0 + r) * Ssz + ss];
  }
  const float cmt = cmv[s] * 6.0f;     // cm / (1.0/6)
  const float gl = gleak[s];
  const float gv = gl * vleak[s];

  // ---- register-resident main tables: this quarter's 8 j-quads ----
  float4 ta[8], tb[8], tw[8];
  {
    const float4* Ab = A4 + (qt * 8) * Ssz + s;
    const float4* Bb = B4 + (qt * 8) * Ssz + s;
    const float4* Wb = W4 + (qt * 8) * Ssz + s;
    #pragma unroll
    for (int q = 0; q < 8; ++q) {
      ta[q] = Ab[q * Ssz];
      tb[q] = Bb[q * Ssz];
      tw[q] = Wb[q * Ssz];
    }
  }
  __syncthreads();

  #pragma unroll 1
  for (int cb = 0; cb < BT; cb += R) {
    // ---- sensory partials over this quarter's i-range (4 quads) ----
    float sn[R] = {0.f, 0.f, 0.f, 0.f}, sd[R] = {0.f, 0.f, 0.f, 0.f};
    #pragma unroll
    for (int q = 0; q < 4; ++q) {
      int iq = qt * 4 + q;
      float4 a4 = A4s[iq * Ssz + s];
      float4 b4 = B4s[iq * Ssz + s];
      float4 w4 = W4s[iq * Ssz + s];
      float4 xq[R];
      #pragma unroll
      for (int r = 0; r < R; ++r) xq[r] = *(const float4*)&xsh[cb + r][iq * 4];
      #pragma unroll
      for (int jj = 0; jj < 4; ++jj) {
        float av = (&a4.x)[jj], bv = (&b4.x)[jj], wv = (&w4.x)[jj];
        #pragma unroll
        for (int r = 0; r < R; ++r) {
          float arg = fmaf(av, (&xq[r].x)[jj], bv);
          float u = __builtin_amdgcn_exp2f(arg);
          float sig = __builtin_amdgcn_rcpf(1.0f + u);
          sn[r] = fmaf(wv, sig, sn[r]);
          sd[r] = fmaf(fabsf(wv), sig, sd[r]);
        }
      }
    }

    // ---- 6 ODE unfolds over this chunk's R rows ----
    #pragma unroll 1
    for (int it = 0; it < 6; ++it) {
      float num[R], den[R];
      #pragma unroll
      for (int r = 0; r < R; ++r) { num[r] = sn[r]; den[r] = sd[r]; }

      // double-buffered broadcast reads of v
      float4 vc[R];
      #pragma unroll
      for (int r = 0; r < R; ++r) vc[r] = *(const float4*)&vsh[cb + r][qt * 32];
      #pragma unroll
      for (int q8 = 0; q8 < 8; ++q8) {
        float4 vn_[R];
        if (q8 < 7) {
          #pragma unroll
          for (int r = 0; r < R; ++r) vn_[r] = *(const float4*)&vsh[cb + r][qt * 32 + (q8 + 1) * 4];
        }
        #pragma unroll
        for (int jj = 0; jj < 4; ++jj) {
          float av = (&ta[q8].x)[jj], bv = (&tb[q8].x)[jj], wv = (&tw[q8].x)[jj];
          #pragma unroll
          for (int r = 0; r < R; ++r) {
            float arg = fmaf(av, (&vc[r].x)[jj], bv);
            float u = __builtin_amdgcn_exp2f(arg);
            float sig = __builtin_amdgcn_rcpf(1.0f + u);
            num[r] = fmaf(wv, sig, num[r]);
            den[r] = fmaf(fabsf(wv), sig, den[r]);
          }
        }
        if (q8 < 7) {
          #pragma unroll
          for (int r = 0; r < R; ++r) vc[r] = vn_[r];
        }
      }

      #pragma unroll
      for (int r = 0; r < R; ++r) { redn[qt][r][s] = num[r]; redd[qt][r][s] = den[r]; }
      __syncthreads();
      // quarter qt finalizes row cb+qt
      float fn = redn[0][qt][s] + redn[1][qt][s] + redn[2][qt][s] + redn[3][qt][s];
      float fd = redd[0][qt][s] + redd[1][qt][s] + redd[2][qt][s] + redd[3][qt][s];
      float vo = vsh[cb + qt][s];
      float nn = fmaf(cmt, vo, gv) + fn;
      float dd = cmt + gl + fd + 1e-8f;
      float vnew = nn * __builtin_amdgcn_rcpf(dd);
      __syncthreads();                 // all redn reads done; all prior vsh reads done
      vsh[cb + qt][s] = vnew;
      __syncthreads();                 // new v visible for next unfold
    }
  }

  // ---- outputs: [B*32] motor affine, then [B*128] v_pre ----
  for (int k = t; k < BT * Ssz; k += NT) {
    int r = k >> 7, ss = k & 127;
    out[Bsz * MOTOR + (b0 + r) * Ssz + ss] = vsh[r][ss];
  }
  for (int k = t; k < BT * MOTOR; k += NT) {
    int r = k >> 5, m = k & 31;
    out[(b0 + r) * MOTOR + m] = fmaf(vsh[r][m], ow[m], ob[m]);
  }
}

extern "C" void kernel_launch(void* const* d_in, const int* in_sizes, int n_in,
                              void* d_out, int out_size, void* d_ws, size_t ws_size,
                              hipStream_t stream) {
  const float* inputs = (const float*)d_in[0];
  const float* states = (const float*)d_in[1];
  const float* gleak  = (const float*)d_in[2];
  const float* vleak  = (const float*)d_in[3];
  const float* cmv    = (const float*)d_in[4];
  const float* w      = (const float*)d_in[5];
  const float* sigma  = (const float*)d_in[6];
  const float* mu     = (const float*)d_in[7];
  const float* erev   = (const float*)d_in[8];
  const float* sw     = (const float*)d_in[9];
  const float* ssig   = (const float*)d_in[10];
  const float* smu    = (const float*)d_in[11];
  const float* serev  = (const float*)d_in[12];
  const float* smask  = (const float*)d_in[13];
  const float* ssmask = (const float*)d_in[14];
  const float* iw     = (const float*)d_in[15];
  const float* ib     = (const float*)d_in[16];
  const float* ow     = (const float*)d_in[17];
  const float* ob     = (const float*)d_in[18];

  char* ws = (char*)d_ws;
  float4* A4  = (float4*)(ws);                   // 32*128*16 = 65536
  float4* B4  = (float4*)(ws + 65536);           // 65536
  float4* W4  = (float4*)(ws + 131072);          // 65536
  float4* A4s = (float4*)(ws + 196608);          // 16*128*16 = 32768
  float4* B4s = (float4*)(ws + 229376);          // 32768
  float4* W4s = (float4*)(ws + 262144);          // 32768  (total 294912 B)
  float* out = (float*)d_out;

  constexpr int prep_items = (Ssz / 4) * Ssz + (Isz / 4) * Ssz;   // 6144
  ltc_prep<<<(prep_items + 255) / 256, 256, 0, stream>>>(
      w, sigma, mu, erev, smask, sw, ssig, smu, serev, ssmask, A4, B4, W4, A4s, B4s, W4s);
  ltc_main<<<Bsz / BT, NT, 0, stream>>>(
      inputs, states, gleak, vleak, cmv, iw, ib, ow, ob, A4, B4, W4, A4s, B4s, W4s, out);
}